// Round 3
// baseline (1649.642 us; speedup 1.0000x reference)
//
#include <hip/hip_runtime.h>
#include <math.h>

#define Bb 2
#define Ss 2048
#define Dd 1024
#define Hh 16
#define DKk 64
#define BSn (Bb*Ss)

// ---------------------------------------------------------------------------
// Tiled fp32 GEMM: Out = X @ W + bias, 64x64 tile, 256 threads, 4x4/thread.
// mode 0: Out is [BS, D] row-major (output projection -> d_out)
// mode 1: Out is [B, H, S, DK] with RoPE applied (Q, K)
// mode 2: Out is [B, H, S, DK] no RoPE (V)
// ---------------------------------------------------------------------------
__global__ __launch_bounds__(256)
void gemm_kernel(const float* __restrict__ X, const float* __restrict__ W,
                 const float* __restrict__ bias, float* __restrict__ Out,
                 int mode)
{
    __shared__ float Xs[64][17];   // [row][kk]
    __shared__ float Ws[16][64];   // [kk][col]

    const int tid = threadIdx.x;
    const int tx = tid & 15, ty = tid >> 4;
    const int n0 = blockIdx.x * 64;
    const int m0 = blockIdx.y * 64;

    float acc[4][4];
#pragma unroll
    for (int r = 0; r < 4; ++r)
#pragma unroll
        for (int c = 0; c < 4; ++c) acc[r][c] = 0.f;

    for (int k0 = 0; k0 < Dd; k0 += 16) {
        // stage X 64x16 and W 16x64
        {
            int row = tid >> 2, c4 = (tid & 3) * 4;
            float4 xv = *(const float4*)(&X[(size_t)(m0 + row) * Dd + k0 + c4]);
            Xs[row][c4 + 0] = xv.x; Xs[row][c4 + 1] = xv.y;
            Xs[row][c4 + 2] = xv.z; Xs[row][c4 + 3] = xv.w;
            int kk = tid >> 4, wc = (tid & 15) * 4;
            float4 wv = *(const float4*)(&W[(size_t)(k0 + kk) * Dd + n0 + wc]);
            Ws[kk][wc + 0] = wv.x; Ws[kk][wc + 1] = wv.y;
            Ws[kk][wc + 2] = wv.z; Ws[kk][wc + 3] = wv.w;
        }
        __syncthreads();
#pragma unroll
        for (int kk = 0; kk < 16; ++kk) {
            float a[4], b[4];
#pragma unroll
            for (int r = 0; r < 4; ++r) a[r] = Xs[ty + 16 * r][kk];
#pragma unroll
            for (int c = 0; c < 4; ++c) b[c] = Ws[kk][tx + 16 * c];
#pragma unroll
            for (int r = 0; r < 4; ++r)
#pragma unroll
                for (int c = 0; c < 4; ++c) acc[r][c] += a[r] * b[c];
        }
        __syncthreads();
    }

    float bvals[4];
#pragma unroll
    for (int c = 0; c < 4; ++c) bvals[c] = bias[n0 + tx + 16 * c];

    if (mode == 0) {
#pragma unroll
        for (int r = 0; r < 4; ++r) {
            int row = m0 + ty + 16 * r;
#pragma unroll
            for (int c = 0; c < 4; ++c)
                Out[(size_t)row * Dd + n0 + tx + 16 * c] = acc[r][c] + bvals[c];
        }
    } else {
        const int h = n0 >> 6;
        const float lg = 0.28782313662425575f;  // ln(10000)/32
#pragma unroll
        for (int r = 0; r < 4; ++r) {
            int row = m0 + ty + 16 * r;
            int b = row >> 11;          // row / S
            int s = row & (Ss - 1);     // row % S
            float v0 = acc[r][0] + bvals[0];
            float v1 = acc[r][1] + bvals[1];
            float v2 = acc[r][2] + bvals[2];
            float v3 = acc[r][3] + bvals[3];
            if (mode == 1) {
                float a0 = (float)s * __expf(-(float)tx * lg);
                float a1 = (float)s * __expf(-(float)(tx + 16) * lg);
                float c0 = cosf(a0), s0 = sinf(a0);
                float c1 = cosf(a1), s1 = sinf(a1);
                float n0v = v0 * c0 - v2 * s0;
                float n2v = v2 * c0 + v0 * s0;
                float n1v = v1 * c1 - v3 * s1;
                float n3v = v3 * c1 + v1 * s1;
                v0 = n0v; v1 = n1v; v2 = n2v; v3 = n3v;
            }
            float* orow = &Out[(((size_t)b * Hh + h) * Ss + s) * DKk];
            orow[tx] = v0; orow[tx + 16] = v1;
            orow[tx + 32] = v2; orow[tx + 48] = v3;
        }
    }
}

// ---------------------------------------------------------------------------
// Flash-style causal attention over [B,H,S,DK] Q/K/V.
// ---------------------------------------------------------------------------
__global__ __launch_bounds__(256)
void attn_kernel(const float* __restrict__ Q, const float* __restrict__ K,
                 const float* __restrict__ V, float* __restrict__ Aout)
{
    __shared__ float Qs[64][65];
    __shared__ float Ks[64][65];
    __shared__ float Vs[64][65];
    __shared__ float Ps[64][65];
    __shared__ float m_sh[64], l_sh[64], alpha_sh[64];

    const int tid = threadIdx.x;
    const int tx = tid & 15, ty = tid >> 4;
    const int qb = blockIdx.x;
    const int bh = blockIdx.y;
    const int q0 = qb * 64;
    const size_t base = (size_t)bh * Ss * DKk;

    // load Q tile
#pragma unroll
    for (int rep = 0; rep < 4; ++rep) {
        int f = tid + rep * 256;          // float4 index
        int r = f >> 4, c4 = (f & 15) * 4;
        float4 qv = *(const float4*)(Q + base + (size_t)(q0 + r) * DKk + c4);
        Qs[r][c4] = qv.x; Qs[r][c4 + 1] = qv.y;
        Qs[r][c4 + 2] = qv.z; Qs[r][c4 + 3] = qv.w;
    }
    if (tid < 64) { m_sh[tid] = -3.0e38f; l_sh[tid] = 0.f; }

    float acc_o[4][4];
#pragma unroll
    for (int r = 0; r < 4; ++r)
#pragma unroll
        for (int c = 0; c < 4; ++c) acc_o[r][c] = 0.f;

    const float scale = 0.125f;  // 1/sqrt(64)

    for (int kb = 0; kb <= qb; ++kb) {
        const int k0 = kb * 64;
        __syncthreads();   // protect Ks/Vs/Ps from previous iteration readers
#pragma unroll
        for (int rep = 0; rep < 4; ++rep) {
            int f = tid + rep * 256;
            int r = f >> 4, c4 = (f & 15) * 4;
            float4 kv = *(const float4*)(K + base + (size_t)(k0 + r) * DKk + c4);
            Ks[r][c4] = kv.x; Ks[r][c4 + 1] = kv.y;
            Ks[r][c4 + 2] = kv.z; Ks[r][c4 + 3] = kv.w;
            float4 vv = *(const float4*)(V + base + (size_t)(k0 + r) * DKk + c4);
            Vs[r][c4] = vv.x; Vs[r][c4 + 1] = vv.y;
            Vs[r][c4 + 2] = vv.z; Vs[r][c4 + 3] = vv.w;
        }
        __syncthreads();

        // S = scale * Q K^T  (+ causal mask)
        float accs[4][4];
#pragma unroll
        for (int r = 0; r < 4; ++r)
#pragma unroll
            for (int c = 0; c < 4; ++c) accs[r][c] = 0.f;
#pragma unroll 8
        for (int d = 0; d < 64; ++d) {
            float a[4], b[4];
#pragma unroll
            for (int r = 0; r < 4; ++r) a[r] = Qs[ty + 16 * r][d];
#pragma unroll
            for (int c = 0; c < 4; ++c) b[c] = Ks[tx + 16 * c][d];
#pragma unroll
            for (int r = 0; r < 4; ++r)
#pragma unroll
                for (int c = 0; c < 4; ++c) accs[r][c] += a[r] * b[c];
        }
#pragma unroll
        for (int r = 0; r < 4; ++r) {
            int qi = q0 + ty + 16 * r;
#pragma unroll
            for (int c = 0; c < 4; ++c) {
                int ki = k0 + tx + 16 * c;
                float sv = accs[r][c] * scale;
                if (ki > qi) sv = -1.0e9f;
                Ps[ty + 16 * r][tx + 16 * c] = sv;
            }
        }
        __syncthreads();

        // online softmax, one thread per query row
        if (tid < 64) {
            float m_old = m_sh[tid];
            float bm = m_old;
#pragma unroll 8
            for (int j = 0; j < 64; ++j) bm = fmaxf(bm, Ps[tid][j]);
            float alpha = __expf(m_old - bm);
            float sum = 0.f;
#pragma unroll 8
            for (int j = 0; j < 64; ++j) {
                float p = __expf(Ps[tid][j] - bm);
                Ps[tid][j] = p;
                sum += p;
            }
            m_sh[tid] = bm;
            l_sh[tid] = l_sh[tid] * alpha + sum;
            alpha_sh[tid] = alpha;
        }
        __syncthreads();

        // O = alpha*O + P @ V
        float al[4];
#pragma unroll
        for (int r = 0; r < 4; ++r) al[r] = alpha_sh[ty + 16 * r];
#pragma unroll
        for (int r = 0; r < 4; ++r)
#pragma unroll
            for (int c = 0; c < 4; ++c) acc_o[r][c] *= al[r];
#pragma unroll 8
        for (int j = 0; j < 64; ++j) {
            float a[4], b[4];
#pragma unroll
            for (int r = 0; r < 4; ++r) a[r] = Ps[ty + 16 * r][j];
#pragma unroll
            for (int c = 0; c < 4; ++c) b[c] = Vs[j][tx + 16 * c];
#pragma unroll
            for (int r = 0; r < 4; ++r)
#pragma unroll
                for (int c = 0; c < 4; ++c) acc_o[r][c] += a[r] * b[c];
        }
    }
    __syncthreads();

    const int b = bh / Hh, h = bh % Hh;
#pragma unroll
    for (int r = 0; r < 4; ++r) {
        int i = ty + 16 * r;
        float inv = 1.0f / l_sh[i];
        float* orow = &Aout[((size_t)b * Ss + (q0 + i)) * Dd + h * DKk];
#pragma unroll
        for (int c = 0; c < 4; ++c) orow[tx + 16 * c] = acc_o[r][c] * inv;
    }
}

extern "C" void kernel_launch(void* const* d_in, const int* in_sizes, int n_in,
                              void* d_out, int out_size, void* d_ws, size_t ws_size,
                              hipStream_t stream) {
    (void)in_sizes; (void)n_in; (void)out_size;
    const float* q  = (const float*)d_in[0];
    const float* k  = (const float*)d_in[1];
    const float* v  = (const float*)d_in[2];
    // d_in[3] = mask (tril causal) -- enforced analytically in attn_kernel
    const float* Wq = (const float*)d_in[4];
    const float* bq = (const float*)d_in[5];
    const float* Wk = (const float*)d_in[6];
    const float* bk = (const float*)d_in[7];
    const float* Wv = (const float*)d_in[8];
    const float* bv = (const float*)d_in[9];
    const float* Wo = (const float*)d_in[10];
    const float* bo = (const float*)d_in[11];
    float* out = (float*)d_out;

    const size_t elems = (size_t)BSn * Dd;
    if (ws_size < 4 * elems * sizeof(float)) return;  // need 64 MB scratch
    float* Qr = (float*)d_ws;
    float* Kr = Qr + elems;
    float* Vr = Kr + elems;
    float* Ar = Vr + elems;

    dim3 gg(Dd / 64, BSn / 64), tt(256);
    gemm_kernel<<<gg, tt, 0, stream>>>(q, Wq, bq, Qr, 1);
    gemm_kernel<<<gg, tt, 0, stream>>>(k, Wk, bk, Kr, 1);
    gemm_kernel<<<gg, tt, 0, stream>>>(v, Wv, bv, Vr, 2);
    dim3 ga(Ss / 64, Bb * Hh);
    attn_kernel<<<ga, tt, 0, stream>>>(Qr, Kr, Vr, Ar);
    gemm_kernel<<<gg, tt, 0, stream>>>(Ar, Wo, bo, out, 0);
}

// Round 4
// 860.241 us; speedup vs baseline: 1.9177x; 1.9177x over previous
//
#include <hip/hip_runtime.h>
#include <hip/hip_bf16.h>
#include <math.h>

#define Bb 2
#define Ss 2048
#define Dd 1024
#define Hh 16
#define DKk 64
#define BSn (Bb*Ss)

typedef unsigned short u16;
typedef __attribute__((ext_vector_type(8))) short frag_ab;   // 8 bf16
typedef __attribute__((ext_vector_type(4))) float frag_cd;   // 4 f32

static __device__ __forceinline__ u16 f2bf(float x) {
    __hip_bfloat16 h = __float2bfloat16(x);
    return *reinterpret_cast<u16*>(&h);
}

// ---------------------------------------------------------------------------
// Tiled fp32 GEMM: Out = X @ W + bias, 64x64 tile, 256 threads, 4x4/thread.
// mode 0: fp32 Out [BS, D]                      (output projection)
// mode 1: bf16 Out [B,H,S,DK], RoPE + 1/8 scale (Q)
// mode 3: bf16 Out [B,H,S,DK], RoPE             (K)
// mode 2: bf16 Out [B,H,DK,S] via LDS transpose (V^T for attention B-frags)
// ---------------------------------------------------------------------------
__global__ __launch_bounds__(256)
void gemm_kernel(const float* __restrict__ X, const float* __restrict__ W,
                 const float* __restrict__ bias, float* __restrict__ OutF,
                 u16* __restrict__ OutB, int mode)
{
    __shared__ float Xs[64][17];
    __shared__ float Ws[16][64];
    __shared__ u16 Tb[64 * 72];     // mode-2 transpose staging

    const int tid = threadIdx.x;
    const int tx = tid & 15, ty = tid >> 4;
    const int n0 = blockIdx.x * 64;
    const int m0 = blockIdx.y * 64;

    float acc[4][4];
#pragma unroll
    for (int r = 0; r < 4; ++r)
#pragma unroll
        for (int c = 0; c < 4; ++c) acc[r][c] = 0.f;

    for (int k0 = 0; k0 < Dd; k0 += 16) {
        {
            int row = tid >> 2, c4 = (tid & 3) * 4;
            float4 xv = *(const float4*)(&X[(size_t)(m0 + row) * Dd + k0 + c4]);
            Xs[row][c4 + 0] = xv.x; Xs[row][c4 + 1] = xv.y;
            Xs[row][c4 + 2] = xv.z; Xs[row][c4 + 3] = xv.w;
            int kk = tid >> 4, wc = (tid & 15) * 4;
            float4 wv = *(const float4*)(&W[(size_t)(k0 + kk) * Dd + n0 + wc]);
            Ws[kk][wc + 0] = wv.x; Ws[kk][wc + 1] = wv.y;
            Ws[kk][wc + 2] = wv.z; Ws[kk][wc + 3] = wv.w;
        }
        __syncthreads();
#pragma unroll
        for (int kk = 0; kk < 16; ++kk) {
            float a[4], b[4];
#pragma unroll
            for (int r = 0; r < 4; ++r) a[r] = Xs[ty + 16 * r][kk];
#pragma unroll
            for (int c = 0; c < 4; ++c) b[c] = Ws[kk][tx + 16 * c];
#pragma unroll
            for (int r = 0; r < 4; ++r)
#pragma unroll
                for (int c = 0; c < 4; ++c) acc[r][c] += a[r] * b[c];
        }
        __syncthreads();
    }

    float bvals[4];
#pragma unroll
    for (int c = 0; c < 4; ++c) bvals[c] = bias[n0 + tx + 16 * c];

    if (mode == 0) {
#pragma unroll
        for (int r = 0; r < 4; ++r) {
            int row = m0 + ty + 16 * r;
#pragma unroll
            for (int c = 0; c < 4; ++c)
                OutF[(size_t)row * Dd + n0 + tx + 16 * c] = acc[r][c] + bvals[c];
        }
    } else if (mode != 2) {
        // Q / K: RoPE epilogue, bf16 [B,H,S,DK]
        const int h = n0 >> 6;
        const float lg = 0.28782313662425575f;  // ln(10000)/32
        const float sc = (mode == 1) ? 0.125f : 1.0f;   // fold 1/sqrt(DK) into Q
#pragma unroll
        for (int r = 0; r < 4; ++r) {
            int row = m0 + ty + 16 * r;
            int b = row >> 11;
            int s = row & (Ss - 1);
            float v0 = acc[r][0] + bvals[0];
            float v1 = acc[r][1] + bvals[1];
            float v2 = acc[r][2] + bvals[2];
            float v3 = acc[r][3] + bvals[3];
            float a0 = (float)s * __expf(-(float)tx * lg);
            float a1 = (float)s * __expf(-(float)(tx + 16) * lg);
            float c0 = cosf(a0), s0 = sinf(a0);
            float c1 = cosf(a1), s1 = sinf(a1);
            float n0v = v0 * c0 - v2 * s0;
            float n2v = v2 * c0 + v0 * s0;
            float n1v = v1 * c1 - v3 * s1;
            float n3v = v3 * c1 + v1 * s1;
            u16* orow = OutB + (((size_t)b * Hh + h) * Ss + s) * DKk;
            orow[tx]      = f2bf(n0v * sc);
            orow[tx + 16] = f2bf(n1v * sc);
            orow[tx + 32] = f2bf(n2v * sc);
            orow[tx + 48] = f2bf(n3v * sc);
        }
    } else {
        // V: transpose to bf16 [B,H,DK,S] through LDS, coalesced 16B stores
        const int h = n0 >> 6;
        const int b = m0 >> 11, s0 = m0 & (Ss - 1);
#pragma unroll
        for (int r = 0; r < 4; ++r)
#pragma unroll
            for (int c = 0; c < 4; ++c)
                Tb[(tx + 16 * c) * 72 + ty + 16 * r] = f2bf(acc[r][c] + bvals[c]);
        __syncthreads();
#pragma unroll
        for (int rep = 0; rep < 2; ++rep) {
            int g = tid + rep * 256;
            int d = g >> 3, s8 = (g & 7) * 8;
            *(uint4*)&OutB[(((size_t)b * Hh + h) * DKk + d) * Ss + s0 + s8] =
                *(uint4*)&Tb[d * 72 + s8];
        }
    }
}

// ---------------------------------------------------------------------------
// MFMA flash attention. Block = 64-query tile x one (b,h). 4 waves x 16 rows.
// Q pre-scaled by 1/8; Q,K bf16 [B,H,S,DK]; Vt bf16 [B,H,DK,S].
// Softmax state in registers (rows replicated across 16 lanes of a quad-group,
// reduced with shfl_xor); P round-trips wave-private LDS into A-layout.
// ---------------------------------------------------------------------------
__global__ __launch_bounds__(256)
void attn_mfma(const u16* __restrict__ Q, const u16* __restrict__ K,
               const u16* __restrict__ Vt, float* __restrict__ Aout)
{
    __shared__ u16 Qs[64 * 72];
    __shared__ u16 Ks[64 * 72];
    __shared__ u16 Vs[64 * 72];     // Vt tile: [d][j]
    __shared__ u16 Ps[4 * 16 * 72]; // per-wave P strip

    const int tid = threadIdx.x;
    const int wv = tid >> 6;
    const int lane = tid & 63;
    const int l16 = lane & 15;
    const int quad = lane >> 4;

    const int qb = blockIdx.x, bh = blockIdx.y;
    const int q0 = qb * 64;
    const size_t qkbase = (size_t)bh * Ss * DKk;
    const size_t vbase  = (size_t)bh * DKk * Ss;

    // stage Q tile (64 x 64 bf16)
#pragma unroll
    for (int rep = 0; rep < 2; ++rep) {
        int g = tid + rep * 256;
        int row = g >> 3, c8 = (g & 7) * 8;
        *(uint4*)&Qs[row * 72 + c8] =
            *(const uint4*)&Q[qkbase + (size_t)(q0 + row) * DKk + c8];
    }

    float m_r[4], l_r[4];
#pragma unroll
    for (int r = 0; r < 4; ++r) { m_r[r] = -3.0e38f; l_r[r] = 0.f; }
    frag_cd of[4];
#pragma unroll
    for (int n = 0; n < 4; ++n) of[n] = (frag_cd){0.f, 0.f, 0.f, 0.f};

    for (int kb = 0; kb <= qb; ++kb) {
        const int k0 = kb * 64;
        __syncthreads();           // prev-iter readers done before restage
#pragma unroll
        for (int rep = 0; rep < 2; ++rep) {
            int g = tid + rep * 256;
            int row = g >> 3, c8 = (g & 7) * 8;
            *(uint4*)&Ks[row * 72 + c8] =
                *(const uint4*)&K[qkbase + (size_t)(k0 + row) * DKk + c8];
            *(uint4*)&Vs[row * 72 + c8] =
                *(const uint4*)&Vt[vbase + (size_t)row * Ss + k0 + c8];
        }
        __syncthreads();

        // S = (Q/8) K^T : 4 col-subtiles x 2 d-halves
        frag_cd sf[4];
#pragma unroll
        for (int n = 0; n < 4; ++n) sf[n] = (frag_cd){0.f, 0.f, 0.f, 0.f};
#pragma unroll
        for (int h2 = 0; h2 < 2; ++h2) {
            frag_ab qa = *(const frag_ab*)&Qs[(wv * 16 + l16) * 72 + h2 * 32 + quad * 8];
#pragma unroll
            for (int n = 0; n < 4; ++n) {
                frag_ab kf = *(const frag_ab*)&Ks[(n * 16 + l16) * 72 + h2 * 32 + quad * 8];
                sf[n] = __builtin_amdgcn_mfma_f32_16x16x32_bf16(qa, kf, sf[n], 0, 0, 0);
            }
        }

        if (kb == qb) {            // causal mask only on diagonal tile
#pragma unroll
            for (int r = 0; r < 4; ++r) {
                int qi = wv * 16 + quad * 4 + r;
#pragma unroll
                for (int n = 0; n < 4; ++n)
                    if (n * 16 + l16 > qi) sf[n][r] = -1.0e30f;
            }
        }

        // online softmax, all in registers
        float alpha[4];
#pragma unroll
        for (int r = 0; r < 4; ++r) {
            float mx = m_r[r];
#pragma unroll
            for (int n = 0; n < 4; ++n) mx = fmaxf(mx, sf[n][r]);
#pragma unroll
            for (int off = 1; off < 16; off <<= 1) mx = fmaxf(mx, __shfl_xor(mx, off));
            float a = __expf(m_r[r] - mx);
            m_r[r] = mx;
            float sum = 0.f;
#pragma unroll
            for (int n = 0; n < 4; ++n) {
                float p = __expf(sf[n][r] - mx);
                sf[n][r] = p;
                sum += p;
            }
#pragma unroll
            for (int off = 1; off < 16; off <<= 1) sum += __shfl_xor(sum, off);
            l_r[r] = l_r[r] * a + sum;
            alpha[r] = a;
        }
#pragma unroll
        for (int n = 0; n < 4; ++n)
#pragma unroll
            for (int r = 0; r < 4; ++r) of[n][r] *= alpha[r];

        // P (C-layout) -> wave-private LDS -> A-layout bf16
#pragma unroll
        for (int n = 0; n < 4; ++n)
#pragma unroll
            for (int r = 0; r < 4; ++r)
                Ps[(wv * 16 + quad * 4 + r) * 72 + n * 16 + l16] = f2bf(sf[n][r]);
        __threadfence_block();

        // O += P @ V
#pragma unroll
        for (int h2 = 0; h2 < 2; ++h2) {
            frag_ab pa = *(const frag_ab*)&Ps[(wv * 16 + l16) * 72 + h2 * 32 + quad * 8];
#pragma unroll
            for (int n = 0; n < 4; ++n) {
                frag_ab vf = *(const frag_ab*)&Vs[(n * 16 + l16) * 72 + h2 * 32 + quad * 8];
                of[n] = __builtin_amdgcn_mfma_f32_16x16x32_bf16(pa, vf, of[n], 0, 0, 0);
            }
        }
    }

    const int b = bh >> 4, h = bh & 15;
#pragma unroll
    for (int r = 0; r < 4; ++r) {
        float inv = 1.f / l_r[r];
        int row = q0 + wv * 16 + quad * 4 + r;
        float* orow = Aout + ((size_t)b * Ss + row) * Dd + h * DKk;
#pragma unroll
        for (int n = 0; n < 4; ++n) orow[n * 16 + l16] = of[n][r] * inv;
    }
}

extern "C" void kernel_launch(void* const* d_in, const int* in_sizes, int n_in,
                              void* d_out, int out_size, void* d_ws, size_t ws_size,
                              hipStream_t stream) {
    (void)in_sizes; (void)n_in; (void)out_size;
    const float* q  = (const float*)d_in[0];
    const float* k  = (const float*)d_in[1];
    const float* v  = (const float*)d_in[2];
    // d_in[3] = mask (tril causal) -- enforced analytically in attn_mfma
    const float* Wq = (const float*)d_in[4];
    const float* bq = (const float*)d_in[5];
    const float* Wk = (const float*)d_in[6];
    const float* bk = (const float*)d_in[7];
    const float* Wv = (const float*)d_in[8];
    const float* bv = (const float*)d_in[9];
    const float* Wo = (const float*)d_in[10];
    const float* bo = (const float*)d_in[11];
    float* out = (float*)d_out;

    const size_t E = (size_t)Bb * Hh * Ss * DKk;      // 4.19M elems
    const size_t need = 3 * E * sizeof(u16) + (size_t)BSn * Dd * sizeof(float);
    if (ws_size < need) return;                        // ~42 MB
    u16* Qb  = (u16*)d_ws;
    u16* Kb  = Qb + E;
    u16* Vtb = Kb + E;
    float* Ar = (float*)(Vtb + E);

    dim3 gg(Dd / 64, BSn / 64), tt(256);
    gemm_kernel<<<gg, tt, 0, stream>>>(q, Wq, bq, nullptr, Qb, 1);
    gemm_kernel<<<gg, tt, 0, stream>>>(k, Wk, bk, nullptr, Kb, 3);
    gemm_kernel<<<gg, tt, 0, stream>>>(v, Wv, bv, nullptr, Vtb, 2);
    dim3 ga(Ss / 64, Bb * Hh);
    attn_mfma<<<ga, tt, 0, stream>>>(Qb, Kb, Vtb, Ar);
    gemm_kernel<<<gg, tt, 0, stream>>>(Ar, Wo, bo, out, nullptr, 0);
}

// Round 5
// 415.148 us; speedup vs baseline: 3.9736x; 2.0721x over previous
//
#include <hip/hip_runtime.h>
#include <hip/hip_bf16.h>
#include <math.h>

#define Bb 2
#define Ss 2048
#define Dd 1024
#define Hh 16
#define DKk 64
#define BSn (Bb*Ss)

typedef unsigned short u16;
typedef __attribute__((ext_vector_type(8))) short frag_ab;   // 8 bf16
typedef __attribute__((ext_vector_type(4))) float frag_cd;   // 4 f32

static __device__ __forceinline__ u16 f2bf(float x) {
    __hip_bfloat16 h = __float2bfloat16(x);
    return *reinterpret_cast<u16*>(&h);
}

// ---------------------------------------------------------------------------
// One-shot convert: q,k,v fp32 -> bf16 (straight); W* fp32 [k][n] -> bf16
// transposed [n][k] (so GEMM B-fragments are contiguous 16B LDS reads).
// blocks 0..3071: activations (1024 blocks each, 4096 elems/block)
// blocks 3072..4095: weight transpose (256 64x64 tiles per weight)
// ---------------------------------------------------------------------------
__global__ __launch_bounds__(256)
void convert_kernel(const float* __restrict__ q, const float* __restrict__ k,
                    const float* __restrict__ v,
                    const float* __restrict__ Wq, const float* __restrict__ Wk,
                    const float* __restrict__ Wv, const float* __restrict__ Wo,
                    u16* __restrict__ qb, u16* __restrict__ kb, u16* __restrict__ vb,
                    u16* __restrict__ wqt, u16* __restrict__ wkt,
                    u16* __restrict__ wvt, u16* __restrict__ wot)
{
    __shared__ u16 T[64 * 80];   // stride 80 u16 = 160 B (16B-aligned rows)
    const int tid = threadIdx.x;
    const int bid = blockIdx.x;
    if (bid < 3072) {
        int t = bid >> 10;
        const float* src = (t == 0) ? q : (t == 1) ? k : v;
        u16* dst = (t == 0) ? qb : (t == 1) ? kb : vb;
        size_t base = (size_t)(bid & 1023) * 4096;
#pragma unroll
        for (int i = 0; i < 4; ++i) {
            size_t e = base + (size_t)(tid + i * 256) * 4;
            float4 xv = *(const float4*)(src + e);
            ushort4 o;
            o.x = f2bf(xv.x); o.y = f2bf(xv.y); o.z = f2bf(xv.z); o.w = f2bf(xv.w);
            *(ushort4*)(dst + e) = o;
        }
    } else {
        int wbid = bid - 3072;
        int w = wbid >> 8;
        const float* src = (w == 0) ? Wq : (w == 1) ? Wk : (w == 2) ? Wv : Wo;
        u16* dst = (w == 0) ? wqt : (w == 1) ? wkt : (w == 2) ? wvt : wot;
        int t = wbid & 255;
        int k0 = (t >> 4) * 64, nt0 = (t & 15) * 64;
#pragma unroll
        for (int i = 0; i < 4; ++i) {
            int f = tid + i * 256;
            int kk = f >> 4, nn = (f & 15) * 4;
            float4 xv = *(const float4*)(src + (size_t)(k0 + kk) * Dd + nt0 + nn);
            T[(nn + 0) * 80 + kk] = f2bf(xv.x);
            T[(nn + 1) * 80 + kk] = f2bf(xv.y);
            T[(nn + 2) * 80 + kk] = f2bf(xv.z);
            T[(nn + 3) * 80 + kk] = f2bf(xv.w);
        }
        __syncthreads();
#pragma unroll
        for (int i = 0; i < 2; ++i) {
            int g = tid + i * 256;
            int nn = g >> 3, k8 = (g & 7) * 8;
            *(uint4*)(dst + (size_t)(nt0 + nn) * Dd + k0 + k8) =
                *(const uint4*)&T[nn * 80 + k8];
        }
    }
}

// ---------------------------------------------------------------------------
// bf16 MFMA GEMM: C[m][n] = sum_k X[m][k] * Wt[n][k] + bias[n]
// 128x64 tile, 4 waves (wave = 32 rows x 64 cols), BK=64, 16x16x32 MFMA.
// mode 0: fp32 Out [BS,D]                         (output projection)
// mode 1: bf16 Out [B,H,S,DK], RoPE + 1/8 scale   (Q)
// mode 3: bf16 Out [B,H,S,DK], RoPE               (K)
// mode 2: bf16 Out [B,H,DK,S]                     (V^T, ushort4 packed)
// ---------------------------------------------------------------------------
__global__ __launch_bounds__(256)
void gemm_bf16(const u16* __restrict__ X, const u16* __restrict__ Wt,
               const float* __restrict__ bias, float* __restrict__ OutF,
               u16* __restrict__ OutB, int mode)
{
    __shared__ u16 As[128 * 72];
    __shared__ u16 Bs[64 * 72];

    const int tid = threadIdx.x;
    const int wv = tid >> 6, lane = tid & 63, l16 = lane & 15, quad = lane >> 4;
    const int n0 = blockIdx.x * 64, m0 = blockIdx.y * 128;

    frag_cd acc[2][4];
#pragma unroll
    for (int ms = 0; ms < 2; ++ms)
#pragma unroll
        for (int n = 0; n < 4; ++n) acc[ms][n] = (frag_cd){0.f, 0.f, 0.f, 0.f};

    for (int k0 = 0; k0 < Dd; k0 += 64) {
        __syncthreads();   // prev-iter LDS readers done
#pragma unroll
        for (int p = 0; p < 4; ++p) {
            int idx = tid + p * 256;
            int row = idx >> 3, slot = idx & 7;
            *(uint4*)&As[row * 72 + slot * 8] =
                *(const uint4*)&X[(size_t)(m0 + row) * Dd + k0 + slot * 8];
        }
#pragma unroll
        for (int p = 0; p < 2; ++p) {
            int idx = tid + p * 256;
            int row = idx >> 3, slot = idx & 7;
            *(uint4*)&Bs[row * 72 + slot * 8] =
                *(const uint4*)&Wt[(size_t)(n0 + row) * Dd + k0 + slot * 8];
        }
        __syncthreads();
#pragma unroll
        for (int ks = 0; ks < 2; ++ks) {
            frag_ab a0 = *(const frag_ab*)&As[(wv * 32 + l16) * 72 + ks * 32 + quad * 8];
            frag_ab a1 = *(const frag_ab*)&As[(wv * 32 + 16 + l16) * 72 + ks * 32 + quad * 8];
#pragma unroll
            for (int n = 0; n < 4; ++n) {
                frag_ab b = *(const frag_ab*)&Bs[(n * 16 + l16) * 72 + ks * 32 + quad * 8];
                acc[0][n] = __builtin_amdgcn_mfma_f32_16x16x32_bf16(a0, b, acc[0][n], 0, 0, 0);
                acc[1][n] = __builtin_amdgcn_mfma_f32_16x16x32_bf16(a1, b, acc[1][n], 0, 0, 0);
            }
        }
    }

    float bv4[4];
#pragma unroll
    for (int n = 0; n < 4; ++n) bv4[n] = bias[n0 + n * 16 + l16];

    if (mode == 0) {
#pragma unroll
        for (int ms = 0; ms < 2; ++ms)
#pragma unroll
            for (int r = 0; r < 4; ++r) {
                int row = m0 + wv * 32 + ms * 16 + quad * 4 + r;
#pragma unroll
                for (int n = 0; n < 4; ++n)
                    OutF[(size_t)row * Dd + n0 + n * 16 + l16] = acc[ms][n][r] + bv4[n];
            }
    } else if (mode == 2) {
        const int h = n0 >> 6;
        const int b = m0 >> 11;
#pragma unroll
        for (int ms = 0; ms < 2; ++ms) {
            int sbase = (m0 & (Ss - 1)) + wv * 32 + ms * 16 + quad * 4;
#pragma unroll
            for (int n = 0; n < 4; ++n) {
                int d = n * 16 + l16;
                ushort4 o;
                o.x = f2bf(acc[ms][n][0] + bv4[n]);
                o.y = f2bf(acc[ms][n][1] + bv4[n]);
                o.z = f2bf(acc[ms][n][2] + bv4[n]);
                o.w = f2bf(acc[ms][n][3] + bv4[n]);
                *(ushort4*)&OutB[(((size_t)b * Hh + h) * DKk + d) * Ss + sbase] = o;
            }
        }
    } else {
        const int h = n0 >> 6;
        const float lg = 0.28782313662425575f;  // ln(10000)/32
        const float sc = (mode == 1) ? 0.125f : 1.0f;
#pragma unroll
        for (int ms = 0; ms < 2; ++ms)
#pragma unroll
            for (int r = 0; r < 4; ++r) {
                int row = m0 + wv * 32 + ms * 16 + quad * 4 + r;
                int b = row >> 11, s = row & (Ss - 1);
                u16* orow = OutB + (((size_t)b * Hh + h) * Ss + s) * DKk;
#pragma unroll
                for (int n = 0; n < 2; ++n) {
                    int j = n * 16 + l16;
                    float ang = (float)s * __expf(-(float)j * lg);
                    float cv = cosf(ang), sv = sinf(ang);
                    float lo = acc[ms][n][r] + bv4[n];
                    float hi = acc[ms][n + 2][r] + bv4[n + 2];
                    orow[j]      = f2bf((lo * cv - hi * sv) * sc);
                    orow[j + 32] = f2bf((hi * cv + lo * sv) * sc);
                }
            }
    }
}

// ---------------------------------------------------------------------------
// MFMA flash attention (as round 4), output now bf16 [B,S,D].
// ---------------------------------------------------------------------------
__global__ __launch_bounds__(256)
void attn_mfma(const u16* __restrict__ Q, const u16* __restrict__ K,
               const u16* __restrict__ Vt, u16* __restrict__ Aout)
{
    __shared__ u16 Qs[64 * 72];
    __shared__ u16 Ks[64 * 72];
    __shared__ u16 Vs[64 * 72];
    __shared__ u16 Ps[4 * 16 * 72];

    const int tid = threadIdx.x;
    const int wv = tid >> 6;
    const int lane = tid & 63;
    const int l16 = lane & 15;
    const int quad = lane >> 4;

    const int qb = blockIdx.x, bh = blockIdx.y;
    const int q0 = qb * 64;
    const size_t qkbase = (size_t)bh * Ss * DKk;
    const size_t vbase  = (size_t)bh * DKk * Ss;

#pragma unroll
    for (int rep = 0; rep < 2; ++rep) {
        int g = tid + rep * 256;
        int row = g >> 3, c8 = (g & 7) * 8;
        *(uint4*)&Qs[row * 72 + c8] =
            *(const uint4*)&Q[qkbase + (size_t)(q0 + row) * DKk + c8];
    }

    float m_r[4], l_r[4];
#pragma unroll
    for (int r = 0; r < 4; ++r) { m_r[r] = -3.0e38f; l_r[r] = 0.f; }
    frag_cd of[4];
#pragma unroll
    for (int n = 0; n < 4; ++n) of[n] = (frag_cd){0.f, 0.f, 0.f, 0.f};

    for (int kb = 0; kb <= qb; ++kb) {
        const int k0 = kb * 64;
        __syncthreads();
#pragma unroll
        for (int rep = 0; rep < 2; ++rep) {
            int g = tid + rep * 256;
            int row = g >> 3, c8 = (g & 7) * 8;
            *(uint4*)&Ks[row * 72 + c8] =
                *(const uint4*)&K[qkbase + (size_t)(k0 + row) * DKk + c8];
            *(uint4*)&Vs[row * 72 + c8] =
                *(const uint4*)&Vt[vbase + (size_t)row * Ss + k0 + c8];
        }
        __syncthreads();

        frag_cd sf[4];
#pragma unroll
        for (int n = 0; n < 4; ++n) sf[n] = (frag_cd){0.f, 0.f, 0.f, 0.f};
#pragma unroll
        for (int h2 = 0; h2 < 2; ++h2) {
            frag_ab qa = *(const frag_ab*)&Qs[(wv * 16 + l16) * 72 + h2 * 32 + quad * 8];
#pragma unroll
            for (int n = 0; n < 4; ++n) {
                frag_ab kf = *(const frag_ab*)&Ks[(n * 16 + l16) * 72 + h2 * 32 + quad * 8];
                sf[n] = __builtin_amdgcn_mfma_f32_16x16x32_bf16(qa, kf, sf[n], 0, 0, 0);
            }
        }

        if (kb == qb) {
#pragma unroll
            for (int r = 0; r < 4; ++r) {
                int qi = wv * 16 + quad * 4 + r;
#pragma unroll
                for (int n = 0; n < 4; ++n)
                    if (n * 16 + l16 > qi) sf[n][r] = -1.0e30f;
            }
        }

        float alpha[4];
#pragma unroll
        for (int r = 0; r < 4; ++r) {
            float mx = m_r[r];
#pragma unroll
            for (int n = 0; n < 4; ++n) mx = fmaxf(mx, sf[n][r]);
#pragma unroll
            for (int off = 1; off < 16; off <<= 1) mx = fmaxf(mx, __shfl_xor(mx, off));
            float a = __expf(m_r[r] - mx);
            m_r[r] = mx;
            float sum = 0.f;
#pragma unroll
            for (int n = 0; n < 4; ++n) {
                float p = __expf(sf[n][r] - mx);
                sf[n][r] = p;
                sum += p;
            }
#pragma unroll
            for (int off = 1; off < 16; off <<= 1) sum += __shfl_xor(sum, off);
            l_r[r] = l_r[r] * a + sum;
            alpha[r] = a;
        }
#pragma unroll
        for (int n = 0; n < 4; ++n)
#pragma unroll
            for (int r = 0; r < 4; ++r) of[n][r] *= alpha[r];

#pragma unroll
        for (int n = 0; n < 4; ++n)
#pragma unroll
            for (int r = 0; r < 4; ++r)
                Ps[(wv * 16 + quad * 4 + r) * 72 + n * 16 + l16] = f2bf(sf[n][r]);
        __threadfence_block();

#pragma unroll
        for (int h2 = 0; h2 < 2; ++h2) {
            frag_ab pa = *(const frag_ab*)&Ps[(wv * 16 + l16) * 72 + h2 * 32 + quad * 8];
#pragma unroll
            for (int n = 0; n < 4; ++n) {
                frag_ab vf = *(const frag_ab*)&Vs[(n * 16 + l16) * 72 + h2 * 32 + quad * 8];
                of[n] = __builtin_amdgcn_mfma_f32_16x16x32_bf16(pa, vf, of[n], 0, 0, 0);
            }
        }
    }

    const int b = bh >> 4, h = bh & 15;
#pragma unroll
    for (int r = 0; r < 4; ++r) {
        float inv = 1.f / l_r[r];
        int row = q0 + wv * 16 + quad * 4 + r;
        u16* orow = Aout + ((size_t)b * Ss + row) * Dd + h * DKk;
#pragma unroll
        for (int n = 0; n < 4; ++n) orow[n * 16 + l16] = f2bf(of[n][r] * inv);
    }
}

extern "C" void kernel_launch(void* const* d_in, const int* in_sizes, int n_in,
                              void* d_out, int out_size, void* d_ws, size_t ws_size,
                              hipStream_t stream) {
    (void)in_sizes; (void)n_in; (void)out_size;
    const float* q  = (const float*)d_in[0];
    const float* k  = (const float*)d_in[1];
    const float* v  = (const float*)d_in[2];
    // d_in[3] = mask (tril causal) -- enforced analytically in attn_mfma
    const float* Wq = (const float*)d_in[4];
    const float* bq = (const float*)d_in[5];
    const float* Wk = (const float*)d_in[6];
    const float* bk = (const float*)d_in[7];
    const float* Wv = (const float*)d_in[8];
    const float* bv = (const float*)d_in[9];
    const float* Wo = (const float*)d_in[10];
    const float* bo = (const float*)d_in[11];
    float* out = (float*)d_out;

    const size_t E = (size_t)Bb * Ss * Dd;     // 4,194,304
    const size_t Wn = (size_t)Dd * Dd;         // 1,048,576
    const size_t need = (7 * E + 4 * Wn) * sizeof(u16);   // 64 MiB
    if (ws_size < need) return;
    u16* qa  = (u16*)d_ws;
    u16* ka  = qa + E;
    u16* va  = ka + E;
    u16* wqt = va + E;
    u16* wkt = wqt + Wn;
    u16* wvt = wkt + Wn;
    u16* wot = wvt + Wn;
    u16* Qh  = wot + Wn;
    u16* Kh  = Qh + E;
    u16* Vth = Kh + E;
    u16* Abf = Vth + E;

    convert_kernel<<<4096, 256, 0, stream>>>(q, k, v, Wq, Wk, Wv, Wo,
                                             qa, ka, va, wqt, wkt, wvt, wot);
    dim3 gg(Dd / 64, BSn / 128), tt(256);
    gemm_bf16<<<gg, tt, 0, stream>>>(qa, wqt, bq, nullptr, Qh, 1);
    gemm_bf16<<<gg, tt, 0, stream>>>(ka, wkt, bk, nullptr, Kh, 3);
    gemm_bf16<<<gg, tt, 0, stream>>>(va, wvt, bv, nullptr, Vth, 2);
    dim3 ga(Ss / 64, Bb * Hh);
    attn_mfma<<<ga, tt, 0, stream>>>(Qh, Kh, Vth, Abf);
    gemm_bf16<<<gg, tt, 0, stream>>>(Abf, wot, bo, out, nullptr, 0);
}